// Round 3
// baseline (212.313 us; speedup 1.0000x reference)
//
#include <hip/hip_runtime.h>
#include <math.h>

#define B_ 128
#define A_ 8732
#define C_ 21
#define APB 256                       // anchors per block (kernel 1)
#define NBLK ((A_ + APB - 1) / APB)   // 35 blocks per row
#define NPART (B_ * NBLK)             // 4480 partials
#define KPT 35                        // keys per thread in k_select (256 thr)

// ws layout (bytes):
#define OFF_PLOC 0                    // float part_loc[4480]
#define OFF_PPCE 17920                // float part_pce[4480]
#define OFF_PNP  35840                // int   part_np[4480]
#define OFF_RCN  53760                // float row_cneg[128]
#define OFF_RNP  54272                // int   row_np[128]
#define OFF_CEN  57344                // float ce_neg[128*8732]

__global__ __launch_bounds__(256) void k_ce(
        const float* __restrict__ conf, const float* __restrict__ loc,
        const int* __restrict__ lab, const float* __restrict__ gloc,
        float* __restrict__ ce_neg, float* __restrict__ part_loc,
        float* __restrict__ part_pce, int* __restrict__ part_np)
{
    __shared__ float sConf[APB * C_];   // 21504 B
    const int b   = blockIdx.y;
    const int a0  = blockIdx.x * APB;
    const int n   = min(APB, A_ - a0);
    const int tid = threadIdx.x;

    // stage confidences tile, coalesced float4; n*21 is always /4 here (n=256 or 28)
    {
        const size_t base = ((size_t)b * A_ + a0) * C_;
        const int n4 = (n * C_) >> 2;
        const float4* src4 = (const float4*)(conf + base);
        float4* dst4 = (float4*)sConf;
        #pragma unroll
        for (int j = 0; j < 6; j++) {           // 6 independent loads in flight
            const int i = tid + j * 256;
            if (i < n4) dst4[i] = src4[i];
        }
    }
    __syncthreads();

    float pce = 0.f, lloss = 0.f;
    int pcnt = 0;
    if (tid < n) {
        const int a = a0 + tid;
        float v[C_];
        #pragma unroll
        for (int j = 0; j < C_; j++) v[j] = sConf[tid * C_ + j];
        float m = v[0];
        #pragma unroll
        for (int j = 1; j < C_; j++) m = fmaxf(m, v[j]);
        float s = 0.f;
        #pragma unroll
        for (int j = 0; j < C_; j++) s += __expf(v[j] - m);
        const int L = lab[(size_t)b * A_ + a];
        const float ce = __logf(s) + m - v[L];
        const bool pos = (L > 0);
        ce_neg[(size_t)b * A_ + a] = pos ? 0.f : ce;
        if (pos) {
            pce = ce;
            pcnt = 1;
            const float4 lv = ((const float4*)loc)[(size_t)b * A_ + a];
            const float4 gv = ((const float4*)gloc)[(size_t)b * A_ + a];
            float dx = lv.x - gv.x, dy = lv.y - gv.y, dz = lv.z - gv.z, dw = lv.w - gv.w;
            float ax = fabsf(dx), ay = fabsf(dy), az = fabsf(dz), aw = fabsf(dw);
            lloss  = (ax < 1.f) ? 0.5f * dx * dx : ax - 0.5f;
            lloss += (ay < 1.f) ? 0.5f * dy * dy : ay - 0.5f;
            lloss += (az < 1.f) ? 0.5f * dz * dz : az - 0.5f;
            lloss += (aw < 1.f) ? 0.5f * dw * dw : aw - 0.5f;
        }
    }

    #pragma unroll
    for (int off = 32; off > 0; off >>= 1) {
        pce   += __shfl_down(pce, off);
        lloss += __shfl_down(lloss, off);
        pcnt  += __shfl_down(pcnt, off);
    }
    __shared__ float wf[4], wl[4];
    __shared__ int wc[4];
    const int wave = tid >> 6, lane = tid & 63;
    if (lane == 0) { wf[wave] = pce; wl[wave] = lloss; wc[wave] = pcnt; }
    __syncthreads();
    if (tid == 0) {
        const int bid = b * NBLK + blockIdx.x;
        part_loc[bid] = wl[0] + wl[1] + wl[2] + wl[3];
        part_pce[bid] = wf[0] + wf[1] + wf[2] + wf[3];
        part_np[bid]  = wc[0] + wc[1] + wc[2] + wc[3];
    }
}

// exact per-row top-k sum: 2-bit-per-round search on float bit patterns,
// ballot+popcount counting (no LDS reduce fan-in), 4 waves, 256 threads.
__global__ __launch_bounds__(256) void k_select(
        const float* __restrict__ ce_neg, const int* __restrict__ part_np,
        float* __restrict__ row_cneg, int* __restrict__ row_np)
{
    const int b = blockIdx.x;
    const int tid = threadIdx.x;
    const int wave = tid >> 6, lane = tid & 63;
    const float* ce = ce_neg + (size_t)b * A_;

    __shared__ unsigned long long shCnt[4];
    __shared__ float shS[4];
    __shared__ int shNp, shK, shMode;
    __shared__ unsigned shLo, shHi;

    // keys in registers (bit patterns; CE >= 0 so uint order == float order)
    unsigned keys[KPT];
    #pragma unroll
    for (int j = 0; j < KPT; j++) {
        const int i = tid + j * 256;
        keys[j] = (i < A_) ? __float_as_uint(ce[i]) : 0u;
    }

    // row num_pos from 35 per-block partials (wave 0)
    if (wave == 0) {
        int v = (lane < NBLK) ? part_np[b * NBLK + lane] : 0;
        #pragma unroll
        for (int off = 32; off > 0; off >>= 1) v += __shfl_down(v, off);
        if (lane == 0) shNp = v;
    }

    // zero-pass: count & sum of strictly-positive keys
    {
        unsigned c0 = 0; float s0 = 0.f;
        #pragma unroll
        for (int j = 0; j < KPT; j++)
            if (keys[j]) { c0++; s0 += __uint_as_float(keys[j]); }
        #pragma unroll
        for (int off = 32; off > 0; off >>= 1) {
            c0 += __shfl_down(c0, off);
            s0 += __shfl_down(s0, off);
        }
        if (lane == 0) { shCnt[wave] = c0; shS[wave] = s0; }
    }
    __syncthreads();
    if (tid == 0) {
        const int np = shNp;
        const int k = min(3 * np, A_ - np);
        const unsigned cnt0 = (unsigned)(shCnt[0] + shCnt[1] + shCnt[2] + shCnt[3]);
        const float sum0 = shS[0] + shS[1] + shS[2] + shS[3];
        row_np[b] = np;
        if (k <= 0)                    { shMode = 2; row_cneg[b] = 0.f; }
        else if (cnt0 < (unsigned)k)   { shMode = 2; row_cneg[b] = sum0; }
        else { shMode = 0; shK = k; shLo = 0u; shHi = 0x42800000u; }  // CE < 64 certain
    }
    __syncthreads();
    if (shMode == 2) return;

    const int k = shK;
    unsigned lo = shLo, hi = shHi;
    while (hi - lo > 1u) {
        const unsigned w = hi - lo;
        unsigned m1, m2, m3;
        if (w >= 4u) { const unsigned q = w >> 2; m1 = lo + q; m2 = lo + 2*q; m3 = lo + 3*q; }
        else         { m1 = m2 = m3 = lo + (w >> 1); }
        unsigned c1 = 0, c2 = 0, c3 = 0;
        #pragma unroll
        for (int j = 0; j < KPT; j++) {
            c1 += (unsigned)__popcll(__ballot(keys[j] > m1));
            c2 += (unsigned)__popcll(__ballot(keys[j] > m2));
            c3 += (unsigned)__popcll(__ballot(keys[j] > m3));
        }
        if (lane == 0)
            shCnt[wave] = (unsigned long long)c1
                        | ((unsigned long long)c2 << 16)
                        | ((unsigned long long)c3 << 32);
        __syncthreads();
        if (tid == 0) {
            const unsigned long long t = shCnt[0] + shCnt[1] + shCnt[2] + shCnt[3];
            const int C1 = (int)(t & 0xFFFF), C2 = (int)((t >> 16) & 0xFFFF),
                      C3 = (int)((t >> 32) & 0xFFFF);
            unsigned nlo, nhi;
            if      (C3 >= k) { nlo = m3; nhi = hi; }
            else if (C2 >= k) { nlo = m2; nhi = m3; }
            else if (C1 >= k) { nlo = m1; nhi = m2; }
            else              { nlo = lo; nhi = m1; }
            shLo = nlo; shHi = nhi;
        }
        __syncthreads();
        lo = shLo; hi = shHi;
    }

    // kth-largest bit pattern == hi (f(lo) >= k > f(hi), hi == lo+1)
    const unsigned kth = hi;
    unsigned c = 0; float s = 0.f;
    #pragma unroll
    for (int j = 0; j < KPT; j++)
        if (keys[j] > kth) { c++; s += __uint_as_float(keys[j]); }
    #pragma unroll
    for (int off = 32; off > 0; off >>= 1) {
        c += __shfl_down(c, off);
        s += __shfl_down(s, off);
    }
    if (lane == 0) { shCnt[wave] = c; shS[wave] = s; }
    __syncthreads();
    if (tid == 0) {
        const unsigned Cg = (unsigned)(shCnt[0] + shCnt[1] + shCnt[2] + shCnt[3]);
        const float Sg = shS[0] + shS[1] + shS[2] + shS[3];
        row_cneg[b] = Sg + (float)(k - (int)Cg) * __uint_as_float(kth);
    }
}

__global__ __launch_bounds__(1024) void k_final(
        const float* __restrict__ part_loc, const float* __restrict__ part_pce,
        const float* __restrict__ row_cneg, const int* __restrict__ row_np,
        float* __restrict__ out)
{
    const int tid = threadIdx.x;
    const int wave = tid >> 6, lane = tid & 63;
    float s = 0.f;
    for (int i = tid; i < NPART; i += 1024) s += part_loc[i] + part_pce[i];
    int n = 0;
    if (tid < B_) { s += row_cneg[tid]; n = row_np[tid]; }
    #pragma unroll
    for (int off = 32; off > 0; off >>= 1) {
        s += __shfl_down(s, off);
        n += __shfl_down(n, off);
    }
    __shared__ float ws_[16];
    __shared__ int wn_[16];
    if (lane == 0) { ws_[wave] = s; wn_[wave] = n; }
    __syncthreads();
    if (tid == 0) {
        float S = 0.f; int N = 0;
        #pragma unroll
        for (int w = 0; w < 16; w++) { S += ws_[w]; N += wn_[w]; }
        out[0] = S / (float)N;
    }
}

extern "C" void kernel_launch(void* const* d_in, const int* in_sizes, int n_in,
                              void* d_out, int out_size, void* d_ws, size_t ws_size,
                              hipStream_t stream) {
    const float* conf = (const float*)d_in[0];   // (B, A, C) f32
    const float* loc  = (const float*)d_in[1];   // (B, A, 4) f32
    const int*   lab  = (const int*)d_in[2];     // (B, A) i32
    const float* gloc = (const float*)d_in[3];   // (B, A, 4) f32

    char* ws = (char*)d_ws;
    float* part_loc = (float*)(ws + OFF_PLOC);
    float* part_pce = (float*)(ws + OFF_PPCE);
    int*   part_np  = (int*)(ws + OFF_PNP);
    float* row_cneg = (float*)(ws + OFF_RCN);
    int*   row_np   = (int*)(ws + OFF_RNP);
    float* ce_neg   = (float*)(ws + OFF_CEN);

    dim3 g1(NBLK, B_);
    k_ce<<<g1, 256, 0, stream>>>(conf, loc, lab, gloc, ce_neg,
                                 part_loc, part_pce, part_np);
    k_select<<<B_, 256, 0, stream>>>(ce_neg, part_np, row_cneg, row_np);
    k_final<<<1, 1024, 0, stream>>>(part_loc, part_pce, row_cneg, row_np,
                                    (float*)d_out);
}

// Round 4
// 188.922 us; speedup vs baseline: 1.1238x; 1.1238x over previous
//
#include <hip/hip_runtime.h>
#include <math.h>

#define B_ 128
#define A_ 8732
#define C_ 21
#define APB 256                       // anchors per block (kernel 1)
#define NBLK ((A_ + APB - 1) / APB)   // 35 blocks per row
#define NPART (B_ * NBLK)             // 4480 partials
#define KPT 9                         // keys per thread in k_select (1024 thr)

// ws layout (bytes):
#define OFF_PLOC 0                    // float part_loc[4480]
#define OFF_PPCE 17920                // float part_pce[4480]
#define OFF_PNP  35840                // int   part_np[4480]
#define OFF_RCN  53760                // float row_cneg[128]
#define OFF_RNP  54272                // int   row_np[128]
#define OFF_CEN  57344                // float ce_neg[128*8732]

__global__ __launch_bounds__(256) void k_ce(
        const float* __restrict__ conf, const float* __restrict__ loc,
        const int* __restrict__ lab, const float* __restrict__ gloc,
        float* __restrict__ ce_neg, float* __restrict__ part_loc,
        float* __restrict__ part_pce, int* __restrict__ part_np)
{
    __shared__ float sConf[APB * C_];   // 21504 B
    const int b   = blockIdx.y;
    const int a0  = blockIdx.x * APB;
    const int n   = min(APB, A_ - a0);
    const int tid = threadIdx.x;

    // stage confidences tile, coalesced float4; n*21 is /4 here (n=256 or 28)
    {
        const size_t base = ((size_t)b * A_ + a0) * C_;
        const int n4 = (n * C_) >> 2;
        const float4* src4 = (const float4*)(conf + base);
        float4* dst4 = (float4*)sConf;
        #pragma unroll
        for (int j = 0; j < 6; j++) {
            const int i = tid + j * 256;
            if (i < n4) dst4[i] = src4[i];
        }
    }
    __syncthreads();

    float pce = 0.f, lloss = 0.f;
    int pcnt = 0;
    if (tid < n) {
        const int a = a0 + tid;
        float v[C_];
        #pragma unroll
        for (int j = 0; j < C_; j++) v[j] = sConf[tid * C_ + j];
        float m = v[0];
        #pragma unroll
        for (int j = 1; j < C_; j++) m = fmaxf(m, v[j]);
        float s = 0.f;
        #pragma unroll
        for (int j = 0; j < C_; j++) s += __expf(v[j] - m);
        const int L = lab[(size_t)b * A_ + a];
        const float ce = __logf(s) + m - v[L];
        const bool pos = (L > 0);
        ce_neg[(size_t)b * A_ + a] = pos ? 0.f : ce;
        if (pos) {
            pce = ce;
            pcnt = 1;
            const float4 lv = ((const float4*)loc)[(size_t)b * A_ + a];
            const float4 gv = ((const float4*)gloc)[(size_t)b * A_ + a];
            float dx = lv.x - gv.x, dy = lv.y - gv.y, dz = lv.z - gv.z, dw = lv.w - gv.w;
            float ax = fabsf(dx), ay = fabsf(dy), az = fabsf(dz), aw = fabsf(dw);
            lloss  = (ax < 1.f) ? 0.5f * dx * dx : ax - 0.5f;
            lloss += (ay < 1.f) ? 0.5f * dy * dy : ay - 0.5f;
            lloss += (az < 1.f) ? 0.5f * dz * dz : az - 0.5f;
            lloss += (aw < 1.f) ? 0.5f * dw * dw : aw - 0.5f;
        }
    }

    #pragma unroll
    for (int off = 32; off > 0; off >>= 1) {
        pce   += __shfl_down(pce, off);
        lloss += __shfl_down(lloss, off);
        pcnt  += __shfl_down(pcnt, off);
    }
    __shared__ float wf[4], wl[4];
    __shared__ int wc[4];
    const int wave = tid >> 6, lane = tid & 63;
    if (lane == 0) { wf[wave] = pce; wl[wave] = lloss; wc[wave] = pcnt; }
    __syncthreads();
    if (tid == 0) {
        const int bid = b * NBLK + blockIdx.x;
        part_loc[bid] = wl[0] + wl[1] + wl[2] + wl[3];
        part_pce[bid] = wf[0] + wf[1] + wf[2] + wf[3];
        part_np[bid]  = wc[0] + wc[1] + wc[2] + wc[3];
    }
}

// exact per-row top-k sum: quaternary search on float bit patterns (CE >= 0 so
// uint order == float order), ballot+popcount counting, 9 keys/thread (no
// spill), double-buffered per-wave counts -> ONE barrier per round, decision
// computed redundantly by every thread (wave-uniform).
__global__ __launch_bounds__(1024, 2) void k_select(
        const float* __restrict__ ce_neg, const int* __restrict__ part_np,
        float* __restrict__ row_cneg, int* __restrict__ row_np)
{
    const int b = blockIdx.x;
    const int tid = threadIdx.x;
    const int wave = tid >> 6, lane = tid & 63;
    const float* ce = ce_neg + (size_t)b * A_;

    __shared__ unsigned long long shCnt[2][16];
    __shared__ float shS[16];
    __shared__ int shNp;

    // keys in registers
    unsigned keys[KPT];
    #pragma unroll
    for (int j = 0; j < KPT; j++) {
        const int i = tid + j * 1024;
        keys[j] = (i < A_) ? __float_as_uint(ce[i]) : 0u;
    }

    // row num_pos from 35 per-block partials (wave 0)
    if (wave == 0) {
        int v = (lane < NBLK) ? part_np[b * NBLK + lane] : 0;
        #pragma unroll
        for (int off = 32; off > 0; off >>= 1) v += __shfl_down(v, off);
        if (lane == 0) shNp = v;
    }

    // zero-pass: per-wave count & sum of strictly-positive keys (ballot keeps
    // the count scalar; sum via shuffles)
    {
        unsigned c0 = 0; float s0 = 0.f;
        #pragma unroll
        for (int j = 0; j < KPT; j++) {
            c0 += (unsigned)__popcll(__ballot(keys[j] != 0u));
            s0 += __uint_as_float(keys[j]);   // +0.0f when key==0
        }
        #pragma unroll
        for (int off = 32; off > 0; off >>= 1) s0 += __shfl_down(s0, off);
        if (lane == 0) { shCnt[0][wave] = c0; shS[wave] = s0; }
    }
    __syncthreads();

    // every thread computes the (uniform) setup decision
    const int np = shNp;
    const int k = min(3 * np, A_ - np);
    unsigned cnt0 = 0; float sum0 = 0.f;
    #pragma unroll
    for (int w = 0; w < 16; w++) { cnt0 += (unsigned)shCnt[0][w]; sum0 += shS[w]; }

    if (k <= 0) { if (tid == 0) { row_cneg[b] = 0.f; row_np[b] = np; } return; }
    if (cnt0 < (unsigned)k) {
        if (tid == 0) { row_cneg[b] = sum0; row_np[b] = np; }
        return;
    }

    unsigned lo = 0u, hi = 0x42800000u;   // CE < 64.0 certain for this data
    int p = 1;
    while (hi - lo > 1u) {
        const unsigned w = hi - lo;
        unsigned m1, m2, m3;
        if (w >= 4u) { const unsigned q = w >> 2; m1 = lo + q; m2 = lo + 2*q; m3 = lo + 3*q; }
        else         { m1 = m2 = m3 = lo + (w >> 1); }
        unsigned c1 = 0, c2 = 0, c3 = 0;
        #pragma unroll
        for (int j = 0; j < KPT; j++) {
            c1 += (unsigned)__popcll(__ballot(keys[j] > m1));
            c2 += (unsigned)__popcll(__ballot(keys[j] > m2));
            c3 += (unsigned)__popcll(__ballot(keys[j] > m3));
        }
        if (lane == 0)
            shCnt[p][wave] = (unsigned long long)c1
                           | ((unsigned long long)c2 << 16)
                           | ((unsigned long long)c3 << 32);
        __syncthreads();
        unsigned long long t = 0;
        #pragma unroll
        for (int w2 = 0; w2 < 16; w2++) t += shCnt[p][w2];
        const int C1 = (int)(t & 0xFFFF), C2 = (int)((t >> 16) & 0xFFFF),
                  C3 = (int)((t >> 32) & 0xFFFF);
        if      (C3 >= k) { lo = m3; }
        else if (C2 >= k) { lo = m2; hi = m3; }
        else if (C1 >= k) { lo = m1; hi = m2; }
        else              { hi = m1; }
        p ^= 1;
    }

    // kth-largest bit pattern == hi (invariant: count(>lo) >= k > count(>hi))
    const unsigned kth = hi;
    unsigned c = 0; float s = 0.f;
    #pragma unroll
    for (int j = 0; j < KPT; j++) {
        c += (unsigned)__popcll(__ballot(keys[j] > kth));
        s += (keys[j] > kth) ? __uint_as_float(keys[j]) : 0.f;
    }
    #pragma unroll
    for (int off = 32; off > 0; off >>= 1) s += __shfl_down(s, off);
    if (lane == 0) { shCnt[0][wave] = c; shS[wave] = s; }
    __syncthreads();
    if (tid == 0) {
        unsigned Cg = 0; float Sg = 0.f;
        #pragma unroll
        for (int w = 0; w < 16; w++) { Cg += (unsigned)shCnt[0][w]; Sg += shS[w]; }
        row_cneg[b] = Sg + (float)(k - (int)Cg) * __uint_as_float(kth);
        row_np[b] = np;
    }
}

__global__ __launch_bounds__(1024) void k_final(
        const float* __restrict__ part_loc, const float* __restrict__ part_pce,
        const float* __restrict__ row_cneg, const int* __restrict__ row_np,
        float* __restrict__ out)
{
    const int tid = threadIdx.x;
    const int wave = tid >> 6, lane = tid & 63;
    float s = 0.f;
    for (int i = tid; i < NPART; i += 1024) s += part_loc[i] + part_pce[i];
    int n = 0;
    if (tid < B_) { s += row_cneg[tid]; n = row_np[tid]; }
    #pragma unroll
    for (int off = 32; off > 0; off >>= 1) {
        s += __shfl_down(s, off);
        n += __shfl_down(n, off);
    }
    __shared__ float ws_[16];
    __shared__ int wn_[16];
    if (lane == 0) { ws_[wave] = s; wn_[wave] = n; }
    __syncthreads();
    if (tid == 0) {
        float S = 0.f; int N = 0;
        #pragma unroll
        for (int w = 0; w < 16; w++) { S += ws_[w]; N += wn_[w]; }
        out[0] = S / (float)N;
    }
}

extern "C" void kernel_launch(void* const* d_in, const int* in_sizes, int n_in,
                              void* d_out, int out_size, void* d_ws, size_t ws_size,
                              hipStream_t stream) {
    const float* conf = (const float*)d_in[0];   // (B, A, C) f32
    const float* loc  = (const float*)d_in[1];   // (B, A, 4) f32
    const int*   lab  = (const int*)d_in[2];     // (B, A) i32
    const float* gloc = (const float*)d_in[3];   // (B, A, 4) f32

    char* ws = (char*)d_ws;
    float* part_loc = (float*)(ws + OFF_PLOC);
    float* part_pce = (float*)(ws + OFF_PPCE);
    int*   part_np  = (int*)(ws + OFF_PNP);
    float* row_cneg = (float*)(ws + OFF_RCN);
    int*   row_np   = (int*)(ws + OFF_RNP);
    float* ce_neg   = (float*)(ws + OFF_CEN);

    dim3 g1(NBLK, B_);
    k_ce<<<g1, 256, 0, stream>>>(conf, loc, lab, gloc, ce_neg,
                                 part_loc, part_pce, part_np);
    k_select<<<B_, 1024, 0, stream>>>(ce_neg, part_np, row_cneg, row_np);
    k_final<<<1, 1024, 0, stream>>>(part_loc, part_pce, row_cneg, row_np,
                                    (float*)d_out);
}

// Round 5
// 181.991 us; speedup vs baseline: 1.1666x; 1.0381x over previous
//
#include <hip/hip_runtime.h>
#include <math.h>

#define B_ 128
#define A_ 8732
#define C_ 21
#define APB 256                       // anchors per block (kernel 1)
#define NBLK ((A_ + APB - 1) / APB)   // 35 blocks per row
#define NPART (B_ * NBLK)             // 4480 partials
#define KPT 9                         // keys per thread in k_select (1024 thr)

typedef float f4 __attribute__((ext_vector_type(4)));

// ws layout (bytes):
#define OFF_PLOC 0                    // float part_loc[4480]
#define OFF_PPCE 17920                // float part_pce[4480]
#define OFF_PNP  35840                // int   part_np[4480]
#define OFF_SCAL 53760                // {float gsum; int gN; int gticket}
#define OFF_CEN  57344                // float ce_neg[128*8732]

__global__ __launch_bounds__(256) void k_ce(
        const float* __restrict__ conf, const float* __restrict__ loc,
        const int* __restrict__ lab, const float* __restrict__ gloc,
        float* __restrict__ ce_neg, float* __restrict__ part_loc,
        float* __restrict__ part_pce, int* __restrict__ part_np,
        float* __restrict__ gsum, int* __restrict__ gN,
        int* __restrict__ gticket)
{
    __shared__ float sConf[APB * C_];   // 21504 B
    const int b   = blockIdx.y;
    const int a0  = blockIdx.x * APB;
    const int n   = min(APB, A_ - a0);
    const int tid = threadIdx.x;

    // zero the cross-kernel scalars (stream order guarantees visibility to k_select)
    if (b == 0 && blockIdx.x == 0 && tid == 0) { *gsum = 0.f; *gN = 0; *gticket = 0; }

    // prefetch label (independent of the staging loads)
    const int a = a0 + min(tid, n - 1);
    const int L = lab[(size_t)b * A_ + a];

    // stage confidences tile, coalesced nontemporal float4 (read-once stream)
    {
        const size_t base = ((size_t)b * A_ + a0) * C_;
        const int n4 = (n * C_) >> 2;          // n*21 is /4 here (n=256 or 28)
        const f4* src4 = (const f4*)(conf + base);
        f4* dst4 = (f4*)sConf;
        #pragma unroll
        for (int j = 0; j < 6; j++) {
            const int i = tid + j * 256;
            if (i < n4) dst4[i] = __builtin_nontemporal_load(&src4[i]);
        }
    }
    __syncthreads();

    float pce = 0.f, lloss = 0.f;
    int pcnt = 0;
    if (tid < n) {
        float v[C_];
        #pragma unroll
        for (int j = 0; j < C_; j++) v[j] = sConf[tid * C_ + j];
        float m = v[0];
        #pragma unroll
        for (int j = 1; j < C_; j++) m = fmaxf(m, v[j]);
        float s = 0.f;
        #pragma unroll
        for (int j = 0; j < C_; j++) s += __expf(v[j] - m);
        const float ce = __logf(s) + m - v[L];
        const bool pos = (L > 0);
        ce_neg[(size_t)b * A_ + a] = pos ? 0.f : ce;
        if (pos) {
            pce = ce;
            pcnt = 1;
            const float4 lv = ((const float4*)loc)[(size_t)b * A_ + a];
            const float4 gv = ((const float4*)gloc)[(size_t)b * A_ + a];
            float dx = lv.x - gv.x, dy = lv.y - gv.y, dz = lv.z - gv.z, dw = lv.w - gv.w;
            float ax = fabsf(dx), ay = fabsf(dy), az = fabsf(dz), aw = fabsf(dw);
            lloss  = (ax < 1.f) ? 0.5f * dx * dx : ax - 0.5f;
            lloss += (ay < 1.f) ? 0.5f * dy * dy : ay - 0.5f;
            lloss += (az < 1.f) ? 0.5f * dz * dz : az - 0.5f;
            lloss += (aw < 1.f) ? 0.5f * dw * dw : aw - 0.5f;
        }
    }

    #pragma unroll
    for (int off = 32; off > 0; off >>= 1) {
        pce   += __shfl_down(pce, off);
        lloss += __shfl_down(lloss, off);
        pcnt  += __shfl_down(pcnt, off);
    }
    __shared__ float wf[4], wl[4];
    __shared__ int wc[4];
    const int wave = tid >> 6, lane = tid & 63;
    if (lane == 0) { wf[wave] = pce; wl[wave] = lloss; wc[wave] = pcnt; }
    __syncthreads();
    if (tid == 0) {
        const int bid = b * NBLK + blockIdx.x;
        part_loc[bid] = wl[0] + wl[1] + wl[2] + wl[3];
        part_pce[bid] = wf[0] + wf[1] + wf[2] + wf[3];
        part_np[bid]  = wc[0] + wc[1] + wc[2] + wc[3];
    }
}

// blocks 0..127: exact per-row top-k sum (quaternary ballot search, R4 geometry).
// block 128: reduce the 4480 loc/pos-CE partials and total num_pos.
// All 129 blocks contribute via device-scope atomics; last block (ticket)
// writes out[0] = total / num_pos.
__global__ __launch_bounds__(1024, 2) void k_select(
        const float* __restrict__ ce_neg, const float* __restrict__ part_loc,
        const float* __restrict__ part_pce, const int* __restrict__ part_np,
        float* __restrict__ gsum, int* __restrict__ gN,
        int* __restrict__ gticket, float* __restrict__ out)
{
    const int b = blockIdx.x;
    const int tid = threadIdx.x;
    const int wave = tid >> 6, lane = tid & 63;

    __shared__ unsigned long long shCnt[2][16];
    __shared__ float shS[16];
    __shared__ int shNp;

    float contrib = 0.f;   // valid at tid==0 after each branch

    if (b == 128) {
        // partials reduction + num_pos total
        float s = 0.f; int n = 0;
        for (int i = tid; i < NPART; i += 1024) {
            s += part_loc[i] + part_pce[i];
            n += part_np[i];
        }
        #pragma unroll
        for (int off = 32; off > 0; off >>= 1) {
            s += __shfl_down(s, off);
            n += __shfl_down(n, off);
        }
        __shared__ int shN2[16];
        if (lane == 0) { shS[wave] = s; shN2[wave] = n; }
        __syncthreads();
        if (tid == 0) {
            float S = 0.f; int N = 0;
            #pragma unroll
            for (int w = 0; w < 16; w++) { S += shS[w]; N += shN2[w]; }
            contrib = S;
            atomicAdd(gN, N);
        }
    } else {
        const float* ce = ce_neg + (size_t)b * A_;

        // keys in registers (bit patterns; CE >= 0 so uint order == float order)
        unsigned keys[KPT];
        #pragma unroll
        for (int j = 0; j < KPT; j++) {
            const int i = tid + j * 1024;
            keys[j] = (i < A_) ? __float_as_uint(ce[i]) : 0u;
        }

        // row num_pos from 35 per-block partials (wave 0)
        if (wave == 0) {
            int v = (lane < NBLK) ? part_np[b * NBLK + lane] : 0;
            #pragma unroll
            for (int off = 32; off > 0; off >>= 1) v += __shfl_down(v, off);
            if (lane == 0) shNp = v;
        }

        // zero-pass: count & sum of strictly-positive keys
        {
            unsigned c0 = 0; float s0 = 0.f;
            #pragma unroll
            for (int j = 0; j < KPT; j++) {
                c0 += (unsigned)__popcll(__ballot(keys[j] != 0u));
                s0 += __uint_as_float(keys[j]);   // +0.0f when key==0
            }
            #pragma unroll
            for (int off = 32; off > 0; off >>= 1) s0 += __shfl_down(s0, off);
            if (lane == 0) { shCnt[0][wave] = c0; shS[wave] = s0; }
        }
        __syncthreads();

        const int np = shNp;
        const int k = min(3 * np, A_ - np);
        unsigned cnt0 = 0; float sum0 = 0.f;
        #pragma unroll
        for (int w = 0; w < 16; w++) { cnt0 += (unsigned)shCnt[0][w]; sum0 += shS[w]; }

        if (k <= 0) {
            contrib = 0.f;
        } else if (cnt0 < (unsigned)k) {
            contrib = sum0;
        } else {
            unsigned lo = 0u, hi = 0x42800000u;   // CE < 64.0 certain for this data
            int p = 1;
            while (hi - lo > 1u) {
                const unsigned w = hi - lo;
                unsigned m1, m2, m3;
                if (w >= 4u) { const unsigned q = w >> 2; m1 = lo + q; m2 = lo + 2*q; m3 = lo + 3*q; }
                else         { m1 = m2 = m3 = lo + (w >> 1); }
                unsigned c1 = 0, c2 = 0, c3 = 0;
                #pragma unroll
                for (int j = 0; j < KPT; j++) {
                    c1 += (unsigned)__popcll(__ballot(keys[j] > m1));
                    c2 += (unsigned)__popcll(__ballot(keys[j] > m2));
                    c3 += (unsigned)__popcll(__ballot(keys[j] > m3));
                }
                if (lane == 0)
                    shCnt[p][wave] = (unsigned long long)c1
                                   | ((unsigned long long)c2 << 16)
                                   | ((unsigned long long)c3 << 32);
                __syncthreads();
                unsigned long long t = 0;
                #pragma unroll
                for (int w2 = 0; w2 < 16; w2++) t += shCnt[p][w2];
                const int C1 = (int)(t & 0xFFFF), C2 = (int)((t >> 16) & 0xFFFF),
                          C3 = (int)((t >> 32) & 0xFFFF);
                if      (C3 >= k) { lo = m3; }
                else if (C2 >= k) { lo = m2; hi = m3; }
                else if (C1 >= k) { lo = m1; hi = m2; }
                else              { hi = m1; }
                p ^= 1;
            }

            // kth-largest bit pattern == hi (invariant: count(>lo) >= k > count(>hi))
            const unsigned kth = hi;
            unsigned c = 0; float s = 0.f;
            #pragma unroll
            for (int j = 0; j < KPT; j++) {
                c += (unsigned)__popcll(__ballot(keys[j] > kth));
                s += (keys[j] > kth) ? __uint_as_float(keys[j]) : 0.f;
            }
            #pragma unroll
            for (int off = 32; off > 0; off >>= 1) s += __shfl_down(s, off);
            if (lane == 0) { shCnt[0][wave] = c; shS[wave] = s; }
            __syncthreads();
            if (tid == 0) {
                unsigned Cg = 0; float Sg = 0.f;
                #pragma unroll
                for (int w = 0; w < 16; w++) { Cg += (unsigned)shCnt[0][w]; Sg += shS[w]; }
                contrib = Sg + (float)(k - (int)Cg) * __uint_as_float(kth);
            }
        }
    }

    // common epilogue: contribute, ticket, last block finalizes
    if (tid == 0) {
        atomicAdd(gsum, contrib);
        __threadfence();
        const int t = atomicAdd(gticket, 1);
        if (t == 128) {   // all 129 blocks contributed
            const float S = atomicAdd(gsum, 0.f);   // coherent read-back
            const int   N = atomicAdd(gN, 0);
            out[0] = S / (float)N;
        }
    }
}

extern "C" void kernel_launch(void* const* d_in, const int* in_sizes, int n_in,
                              void* d_out, int out_size, void* d_ws, size_t ws_size,
                              hipStream_t stream) {
    const float* conf = (const float*)d_in[0];   // (B, A, C) f32
    const float* loc  = (const float*)d_in[1];   // (B, A, 4) f32
    const int*   lab  = (const int*)d_in[2];     // (B, A) i32
    const float* gloc = (const float*)d_in[3];   // (B, A, 4) f32

    char* ws = (char*)d_ws;
    float* part_loc = (float*)(ws + OFF_PLOC);
    float* part_pce = (float*)(ws + OFF_PPCE);
    int*   part_np  = (int*)(ws + OFF_PNP);
    float* gsum     = (float*)(ws + OFF_SCAL);
    int*   gN       = (int*)(ws + OFF_SCAL + 4);
    int*   gticket  = (int*)(ws + OFF_SCAL + 8);
    float* ce_neg   = (float*)(ws + OFF_CEN);

    dim3 g1(NBLK, B_);
    k_ce<<<g1, 256, 0, stream>>>(conf, loc, lab, gloc, ce_neg,
                                 part_loc, part_pce, part_np,
                                 gsum, gN, gticket);
    k_select<<<129, 1024, 0, stream>>>(ce_neg, part_loc, part_pce, part_np,
                                       gsum, gN, gticket, (float*)d_out);
}